// Round 13
// baseline (117.725 us; speedup 1.0000x reference)
//
#include <hip/hip_runtime.h>
#include <math.h>

typedef __attribute__((ext_vector_type(8))) short bf16x8;   // 8 bf16 (4 VGPRs)
typedef __attribute__((ext_vector_type(4))) float f32x4;    // MFMA acc

#define SQRT3F     1.7320508075688772f
#define SCALE_T    0.17677669529663687f    // 1/sqrt(32)
#define SCALE_M1   0.025515518153991442f   // C_SCALAR/sqrt(32)
#define SCALE_M2   0.014731391274719739f   // C_SCALAR*inv_sqrt3/sqrt(32)
#define SCALE_M34  0.036084391824351615f   // C_SCALAR/4

#define FSTR 40    // feature row stride (shorts): 80 B

__device__ __forceinline__ ushort f2bf(float f) {
    union { float f; unsigned u; } v; v.f = f;
    unsigned u = v.u;
    return (ushort)((u + 0x7FFFu + ((u >> 16) & 1u)) >> 16);
}
__device__ __forceinline__ float bf2f(ushort h) {
    union { unsigned u; float f; } v; v.u = ((unsigned)h) << 16;
    return v.f;
}
// packed f32->bf16 (RNE). Safe ONLY when the consumer is ds_write/global
// (r4-proven). NOT safe feeding MFMA directly (r10 NaN: INLINEASM def is
// opaque to the hazard recognizer -> missing VALU-write->MFMA-read waits).
__device__ __forceinline__ unsigned cvtpk(float lo, float hi) {
    unsigned r;
    asm("v_cvt_pk_bf16_f32 %0, %1, %2" : "=v"(r) : "v"(lo), "v"(hi));
    return r;
}
__device__ __forceinline__ f32x4 mfma(bf16x8 a, bf16x8 b, f32x4 c) {
    return __builtin_amdgcn_mfma_f32_16x16x32_bf16(a, b, c, 0, 0, 0);
}
// ---- sigma-permuted A-fragment packs (NO cross-lane ops) ----
// Hardware k slot kq*8+e holds logical index sigma(kq,e)=(e>>2)*16+kq*4+(e&3).
// B-operands (adjacency, M) are stored with the same sigma on their k axis,
// so stage-1/stage-2 A-frags are pure per-lane cvtpk packs of D-tiles.
// HAZARD-HARDENED (r10/r12): one asm block per fragment, early-clobber
// outputs, trailing s_nop 3 = deterministic VALU->MFMA wait states.
__device__ __forceinline__ bf16x8 frag2(f32x4 A, f32x4 B) {
    union { bf16x8 v; unsigned u[4]; } r;
    asm("v_cvt_pk_bf16_f32 %0, %4, %5\n\t"
        "v_cvt_pk_bf16_f32 %1, %6, %7\n\t"
        "v_cvt_pk_bf16_f32 %2, %8, %9\n\t"
        "v_cvt_pk_bf16_f32 %3, %10, %11\n\t"
        "s_nop 3"
        : "=&v"(r.u[0]), "=&v"(r.u[1]), "=&v"(r.u[2]), "=&v"(r.u[3])
        : "v"(A[0]), "v"(A[1]), "v"(A[2]), "v"(A[3]),
          "v"(B[0]), "v"(B[1]), "v"(B[2]), "v"(B[3]));
    return r.v;
}
__device__ __forceinline__ bf16x8 frag1z(f32x4 A) {
    union { bf16x8 v; unsigned u[4]; } r;
    asm("v_cvt_pk_bf16_f32 %0, %2, %3\n\t"
        "v_cvt_pk_bf16_f32 %1, %4, %5\n\t"
        "s_nop 3"
        : "=&v"(r.u[0]), "=&v"(r.u[1])
        : "v"(A[0]), "v"(A[1]), "v"(A[2]), "v"(A[3]));
    r.u[2] = 0u; r.u[3] = 0u;
    return r.v;
}
// residual + relu, f32 register state
__device__ __forceinline__ void accRelu(f32x4 &S, f32x4 h) {
    S[0] += fmaxf(h[0], 0.f); S[1] += fmaxf(h[1], 0.f);
    S[2] += fmaxf(h[2], 0.f); S[3] += fmaxf(h[3], 0.f);
}

// ---------------------------------------------------------------------------
// Prep (tiny, one-shot): Tbf = bf16(emb@W_s2n * sT)  (100x32)
//   Mbf[lyr][row][64]: SIGMA-PERMUTED k axis — physical col c holds the
//   value for logical u = (c>>5)*32 + ((c&7)>>2)*16 + ((c>>3)&3)*4 + (c&3).
//   rows 0..31 = MsT[w][u], rows 32..47 = MvT[w][u]; logical u>=48 -> 0.
// ---------------------------------------------------------------------------
__global__ void prep_kernel(const float* __restrict__ emb,
                            const float* __restrict__ W_s2n,
                            const float* __restrict__ W1, const float* __restrict__ W2,
                            const float* __restrict__ W3, const float* __restrict__ W4,
                            const float* __restrict__ Ws, const float* __restrict__ Wv,
                            ushort* __restrict__ Tbf, ushort* __restrict__ Mbf)
{
    int idx = blockIdx.x * blockDim.x + threadIdx.x;
    if (idx < 3200) {
        int r = idx >> 5, c = idx & 31;
        float acc = 0.f;
        for (int k = 0; k < 32; ++k) acc += emb[r*32 + k] * W_s2n[k*32 + c];
        Tbf[idx] = f2bf(acc * SCALE_T);
        return;
    }
    idx -= 3200;
    if (idx < 3*48*64) {
        int lyr = idx / 3072, rem = idx % 3072;
        int row = rem >> 6, c = rem & 63;
        // physical col c -> logical u via sigma
        int kc = c >> 5, c5 = c & 31, kq2 = c5 >> 3, e = c5 & 7;
        int u = kc*32 + (e >> 2)*16 + kq2*4 + (e & 3);
        float val = 0.f;
        if (row < 32) {
            int w = row;
            if (u < 32) {
                float a = 0.f;
                for (int k = 0; k < 32; ++k)
                    a += W1[lyr*1024 + u*32 + k] * Ws[lyr*1024 + k*32 + w];
                val = a * SCALE_M1;
            } else if (u < 48) {
                int uu = u - 32; float a = 0.f;
                for (int k = 0; k < 32; ++k)
                    a += W4[lyr*512 + uu*32 + k] * Ws[lyr*1024 + k*32 + w];
                val = a * SCALE_M2;
            }
        } else {
            int w = row - 32;
            if (u < 32) {
                float a = 0.f;
                for (int k = 0; k < 16; ++k)
                    a += W2[lyr*512 + u*16 + k] * Wv[lyr*256 + k*16 + w];
                val = a * SCALE_M34;
            } else if (u < 48) {
                int uu = u - 32; float a = 0.f;
                for (int k = 0; k < 16; ++k)
                    a += W3[lyr*256 + uu*16 + k] * Wv[lyr*256 + k*16 + w];
                val = a * SCALE_M34;
            }
        }
        Mbf[lyr*3072 + row*64 + c] = f2bf(val);
    }
}

// ---------------------------------------------------------------------------
// Fused GNN + MLP: TWO graphs per wave (in-wave ILP); 8 graphs/block;
// 256 blocks. Rationale (r12 post-mortem): co-resident waves run identical
// code -> correlated stalls -> weak TLP. Two independent graph streams
// interleaved in-wave by the list scheduler fill each other's MFMA/pack
// latency deterministically. M fragments shared between the two graphs.
// State in f32 registers; sigma layout; zero LDS/permlane in layer loop.
// ---------------------------------------------------------------------------
__global__ __launch_bounds__(256)
void gnn_kernel(const float* __restrict__ pos, const int* __restrict__ z,
                const ushort* __restrict__ Tbf, const ushort* __restrict__ Mbf,
                const float* __restrict__ Wr1, const float* __restrict__ br1,
                const float* __restrict__ Wr2, const float* __restrict__ br2,
                float* __restrict__ out, int B)
{
    __shared__ __align__(16) char smem[53760];
    ushort* featA = (ushort*)smem;                    // 8*80*40*2 = 51200 B
    float*  hgl   = (float*)(smem + 51200);           // 8*80*4    = 2560 B
    float*  h1    = (float*)smem;                     // 8*256*4   = 8192 B (alias)
    float*  red   = (float*)(smem + 8192);            // 8*128*4   = 4096 B (alias)

    const int tid = threadIdx.x;
    const int wv = tid >> 6, l = tid & 63;
    const int gbase = blockIdx.x*8 + wv*2;            // this wave's 2 graphs
    const int ln = l & 15, kq = l >> 4;

    // s init: F[c][n] = Tbf[z[n]][c]  (transposed scatter, per graph)
    #pragma unroll
    for (int p = 0; p < 2; ++p) {
        ushort* F = featA + (wv*2 + p)*80*FSTR;
        int n = l & 31, h = l >> 5;
        int zg = z[(gbase + p)*32 + n];
        uint4 t0 = *(const uint4*)(Tbf + zg*32 + h*16);
        uint4 t1 = *(const uint4*)(Tbf + zg*32 + h*16 + 8);
        unsigned ua[8] = {t0.x, t0.y, t0.z, t0.w, t1.x, t1.y, t1.z, t1.w};
        #pragma unroll
        for (int q = 0; q < 8; ++q) {
            F[(h*16 + 2*q    )*FSTR + n] = (ushort)ua[q];
            F[(h*16 + 2*q + 1)*FSTR + n] = (ushort)(ua[q] >> 16);
        }
    }

    // register feature state, D-layout: lane=channel, regs=node
    f32x4 Ss[2][2][2];         // [graph][node-tile][s-ch-tile]
    f32x4 Sv[2][2][3];         // [graph][node-tile][spatial i]
    #pragma unroll
    for (int p = 0; p < 2; ++p) {
        ushort* F = featA + (wv*2 + p)*80*FSTR;
        #pragma unroll
        for (int mt = 0; mt < 2; ++mt) {
            #pragma unroll
            for (int wt = 0; wt < 2; ++wt) {
                uint2 d = *(const uint2*)&F[(wt*16 + ln)*FSTR + mt*16 + kq*4];
                Ss[p][mt][wt][0] = bf2f((ushort)(d.x      ));
                Ss[p][mt][wt][1] = bf2f((ushort)(d.x >> 16));
                Ss[p][mt][wt][2] = bf2f((ushort)(d.y      ));
                Ss[p][mt][wt][3] = bf2f((ushort)(d.y >> 16));
            }
            #pragma unroll
            for (int i = 0; i < 3; ++i)
                Sv[p][mt][i] = (f32x4){0.f, 0.f, 0.f, 0.f};
        }
    }

    // adjacency fragments, sigma-permuted k (src = (jj>>2)*16 + kq*4 + (jj&3))
    bf16x8 adjf[2][4][2];      // [graph][component][node-tile]
    #pragma unroll
    for (int p = 0; p < 2; ++p) {
        #pragma unroll
        for (int nt = 0; nt < 2; ++nt) {
            int ng = (gbase + p)*32 + nt*16 + ln;
            float px = pos[3*ng], py = pos[3*ng+1], pz = pos[3*ng+2];
            union { bf16x8 v; ushort s[8]; } o[4];
            #pragma unroll
            for (int jj = 0; jj < 8; ++jj) {
                int j = (gbase + p)*32 + ((jj >> 2) << 4) + kq*4 + (jj & 3);
                float dx = __fsub_rn(px, pos[3*j]);
                float dy = __fsub_rn(py, pos[3*j+1]);
                float dz = __fsub_rn(pz, pos[3*j+2]);
                float d2 = __fadd_rn(__fadd_rn(__fmul_rn(dx,dx), __fmul_rn(dy,dy)),
                                     __fmul_rn(dz,dz));
                bool on = (d2 <= 25.0f) && (d2 > 0.0f);
                float rinv = on ? rsqrtf(d2) * SQRT3F : 0.f;
                o[0].s[jj] = on ? (ushort)0x3F80 : (ushort)0;   // bf16(1.0)
                o[1].s[jj] = f2bf(dx * rinv);
                o[2].s[jj] = f2bf(dy * rinv);
                o[3].s[jj] = f2bf(dz * rinv);
            }
            #pragma unroll
            for (int w = 0; w < 4; ++w) adjf[p][w][nt] = o[w].v;
        }
    }

    const f32x4 z4 = {0.f, 0.f, 0.f, 0.f};

    for (int lay = 0; lay < 3; ++lay) {
        const ushort* Mg = Mbf + lay*3072;
        // M fragments (shared by both graphs; global, L1-hot; sigma baked in)
        bf16x8 bmS0[2], bmS1[2], bmV[2];
        #pragma unroll
        for (int kc = 0; kc < 2; ++kc) {
            bmS0[kc] = *(const bf16x8*)&Mg[(     ln)*64 + kc*32 + kq*8];
            bmS1[kc] = *(const bf16x8*)&Mg[(16 + ln)*64 + kc*32 + kq*8];
            bmV [kc] = *(const bf16x8*)&Mg[(32 + ln)*64 + kc*32 + kq*8];
        }
        // A-frags from register state: pure cvtpk packs (sigma layout)
        bf16x8 fs0[2], fs1[2], fv0[2], fv1[2], fv2[2];
        #pragma unroll
        for (int p = 0; p < 2; ++p) {
            fs0[p] = frag2(Ss[p][0][0], Ss[p][1][0]);
            fs1[p] = frag2(Ss[p][0][1], Ss[p][1][1]);
            fv0[p] = frag2(Sv[p][0][0], Sv[p][1][0]);
            fv1[p] = frag2(Sv[p][0][1], Sv[p][1][1]);
            fv2[p] = frag2(Sv[p][0][2], Sv[p][1][2]);
        }

        bf16x8 agf[2][2][2];   // [graph][node-tile][k-block]

        // ---- scalar path (both graphs interleaved by the scheduler)
        #pragma unroll
        for (int p = 0; p < 2; ++p)
            #pragma unroll
            for (int nt = 0; nt < 2; ++nt) {
                f32x4 T0 = mfma(fs0[p], adjf[p][0][nt], z4);
                f32x4 T1 = mfma(fs1[p], adjf[p][0][nt], z4);
                f32x4 T2 = mfma(fv2[p], adjf[p][3][nt], z4);
                T2 = mfma(fv1[p], adjf[p][2][nt], T2);
                T2 = mfma(fv0[p], adjf[p][1][nt], T2);
                agf[p][nt][0] = frag2(T0, T1);
                agf[p][nt][1] = frag1z(T2);
            }
        {
            f32x4 hs[2][2][2];   // [graph][node-tile][w-tile]
            #pragma unroll
            for (int p = 0; p < 2; ++p)
                #pragma unroll
                for (int mt = 0; mt < 2; ++mt) {
                    hs[p][mt][0] = z4; hs[p][mt][1] = z4;
                }
            #pragma unroll
            for (int kc = 0; kc < 2; ++kc)
                #pragma unroll
                for (int p = 0; p < 2; ++p)
                    #pragma unroll
                    for (int mt = 0; mt < 2; ++mt) {
                        hs[p][mt][0] = mfma(agf[p][mt][kc], bmS0[kc], hs[p][mt][0]);
                        hs[p][mt][1] = mfma(agf[p][mt][kc], bmS1[kc], hs[p][mt][1]);
                    }
            #pragma unroll
            for (int p = 0; p < 2; ++p)
                #pragma unroll
                for (int mt = 0; mt < 2; ++mt) {
                    accRelu(Ss[p][mt][0], hs[p][mt][0]);
                    accRelu(Ss[p][mt][1], hs[p][mt][1]);
                }
        }

        // ---- vector path, one spatial component i at a time
        #pragma unroll
        for (int i = 0; i < 3; ++i) {
            #pragma unroll
            for (int p = 0; p < 2; ++p) {
                bf16x8 fvi = (i == 0) ? fv0[p] : (i == 1) ? fv1[p] : fv2[p];
                #pragma unroll
                for (int nt = 0; nt < 2; ++nt) {
                    f32x4 T0 = mfma(fs0[p], adjf[p][1+i][nt], z4);
                    f32x4 T1 = mfma(fs1[p], adjf[p][1+i][nt], z4);
                    f32x4 T2 = mfma(fvi, adjf[p][0][nt], z4);
                    agf[p][nt][0] = frag2(T0, T1);
                    agf[p][nt][1] = frag1z(T2);
                }
            }
            f32x4 hv[2][2];
            #pragma unroll
            for (int p = 0; p < 2; ++p) { hv[p][0] = z4; hv[p][1] = z4; }
            #pragma unroll
            for (int kc = 0; kc < 2; ++kc)
                #pragma unroll
                for (int p = 0; p < 2; ++p)
                    #pragma unroll
                    for (int mt = 0; mt < 2; ++mt)
                        hv[p][mt] = mfma(agf[p][mt][kc], bmV[kc], hv[p][mt]);
            #pragma unroll
            for (int p = 0; p < 2; ++p)
                #pragma unroll
                for (int mt = 0; mt < 2; ++mt)
                    accRelu(Sv[p][mt][i], hv[p][mt]);
        }
    }

    // write state back to F (bf16) for the pooling pass
    #pragma unroll
    for (int p = 0; p < 2; ++p) {
        ushort* F = featA + (wv*2 + p)*80*FSTR;
        #pragma unroll
        for (int mt = 0; mt < 2; ++mt) {
            #pragma unroll
            for (int wt = 0; wt < 2; ++wt) {
                uint2 w;
                w.x = cvtpk(Ss[p][mt][wt][0], Ss[p][mt][wt][1]);
                w.y = cvtpk(Ss[p][mt][wt][2], Ss[p][mt][wt][3]);
                *(uint2*)&F[(wt*16 + ln)*FSTR + mt*16 + kq*4] = w;
            }
            #pragma unroll
            for (int i = 0; i < 3; ++i) {
                uint2 w;
                w.x = cvtpk(Sv[p][mt][i][0], Sv[p][mt][i][1]);
                w.y = cvtpk(Sv[p][mt][i][2], Sv[p][mt][i][3]);
                *(uint2*)&F[(32 + i*16 + ln)*FSTR + mt*16 + kq*4] = w;
            }
        }
    }

    // wave-local sum-pool -> hgl[graph][80]
    #pragma unroll
    for (int p = 0; p < 2; ++p) {
        ushort* F = featA + (wv*2 + p)*80*FSTR;
        for (int f = l; f < 80; f += 64) {
            const ushort* row;
            if (f < 32) row = &F[f*FSTR];
            else { int c = f - 32, w = c/3, i = c - 3*w; row = &F[(32 + i*16 + w)*FSTR]; }
            const uint* r32 = (const uint*)row;
            float acc = 0.f;
            #pragma unroll
            for (int q = 0; q < 16; ++q) {
                uint u = r32[q];
                acc += bf2f((ushort)u) + bf2f((ushort)(u >> 16));
            }
            hgl[(wv*2 + p)*80 + f] = acc;
        }
    }
    __syncthreads();   // hgl complete; featA (F) dead -> h1/red alias safe

    // --- fused MLP head (block = its 8 graphs) ---
    {
        const int w = tid;
        float acc[8];
        #pragma unroll
        for (int gg = 0; gg < 8; ++gg) acc[gg] = br1[w];
        #pragma unroll 4
        for (int f = 0; f < 80; ++f) {
            float wvv = Wr1[f*256 + w];
            #pragma unroll
            for (int gg = 0; gg < 8; ++gg)
                acc[gg] = fmaf(hgl[gg*80 + f], wvv, acc[gg]);
        }
        #pragma unroll
        for (int gg = 0; gg < 8; ++gg)
            h1[gg*256 + w] = fmaxf(acc[gg], 0.f);
    }
    __syncthreads();
    {
        const int g0 = blockIdx.x * 8;
        const int w2 = tid & 127, kh = tid >> 7;
        const float4* h1v = (const float4*)h1;   // [8][64] float4 view
        float s[8];
        #pragma unroll
        for (int gg = 0; gg < 8; ++gg) s[gg] = 0.f;
        for (int k4 = kh*32; k4 < kh*32 + 32; ++k4) {
            int k = k4 * 4;
            float m0 = Wr2[(size_t)(k+0)*128 + w2];
            float m1 = Wr2[(size_t)(k+1)*128 + w2];
            float m2 = Wr2[(size_t)(k+2)*128 + w2];
            float m3 = Wr2[(size_t)(k+3)*128 + w2];
            #pragma unroll
            for (int gg = 0; gg < 8; ++gg) {
                float4 hh = h1v[gg*64 + k4];
                s[gg] = fmaf(hh.x,m0, fmaf(hh.y,m1, fmaf(hh.z,m2, fmaf(hh.w,m3, s[gg]))));
            }
        }
        if (kh) {
            #pragma unroll
            for (int gg = 0; gg < 8; ++gg) red[gg*128 + w2] = s[gg];
        }
        __syncthreads();
        if (!kh) {
            float b = br2[w2];
            #pragma unroll
            for (int gg = 0; gg < 8; ++gg)
                out[(size_t)(g0+gg)*128 + w2] = s[gg] + red[gg*128 + w2] + b;
        }
    }
}

// ---------------------------------------------------------------------------
extern "C" void kernel_launch(void* const* d_in, const int* in_sizes, int n_in,
                              void* d_out, int out_size, void* d_ws, size_t ws_size,
                              hipStream_t stream)
{
    const float* pos   = (const float*)d_in[0];
    const int*   z     = (const int*)d_in[1];
    const float* emb   = (const float*)d_in[5];
    const float* W_s2n = (const float*)d_in[6];
    const float* W1    = (const float*)d_in[7];
    const float* W2    = (const float*)d_in[8];
    const float* W3    = (const float*)d_in[9];
    const float* W4    = (const float*)d_in[10];
    const float* Ws    = (const float*)d_in[11];
    const float* Wv    = (const float*)d_in[12];
    const float* Wr1   = (const float*)d_in[13];
    const float* br1   = (const float*)d_in[14];
    const float* Wr2   = (const float*)d_in[15];
    const float* br2   = (const float*)d_in[16];
    float* out = (float*)d_out;

    const int B = out_size / 128;      // graphs (2048)

    // workspace: Tbf (3200 shorts) | Mbf (9216 shorts)
    char* p = (char*)d_ws;
    ushort* Tbf = (ushort*)p;  p += 6400;
    ushort* Mbf = (ushort*)p;  p += 18432;

    const int prep_total = 3200 + 3*48*64;
    prep_kernel<<<(prep_total + 255) / 256, 256, 0, stream>>>(
        emb, W_s2n, W1, W2, W3, W4, Ws, Wv, Tbf, Mbf);

    gnn_kernel<<<B / 8, 256, 0, stream>>>(pos, z, Tbf, Mbf,
                                          Wr1, br1, Wr2, br2, out, B);
}

// Round 14
// 110.633 us; speedup vs baseline: 1.0641x; 1.0641x over previous
//
#include <hip/hip_runtime.h>
#include <math.h>

typedef __attribute__((ext_vector_type(8))) short bf16x8;   // 8 bf16 (4 VGPRs)
typedef __attribute__((ext_vector_type(4))) float f32x4;    // MFMA acc

#define SQRT3F     1.7320508075688772f
#define SCALE_T    0.17677669529663687f    // 1/sqrt(32)
#define SCALE_M1   0.025515518153991442f   // C_SCALAR/sqrt(32)
#define SCALE_M2   0.014731391274719739f   // C_SCALAR*inv_sqrt3/sqrt(32)
#define SCALE_M34  0.036084391824351615f   // C_SCALAR/4

#define FSTR 40    // feature row stride (shorts): 80 B

__device__ __forceinline__ ushort f2bf(float f) {
    union { float f; unsigned u; } v; v.f = f;
    unsigned u = v.u;
    return (ushort)((u + 0x7FFFu + ((u >> 16) & 1u)) >> 16);
}
__device__ __forceinline__ float bf2f(ushort h) {
    union { unsigned u; float f; } v; v.u = ((unsigned)h) << 16;
    return v.f;
}
// packed f32->bf16 (RNE). Safe ONLY when the consumer is ds_write/global
// (r4-proven). NOT safe feeding MFMA directly (r10 NaN: INLINEASM def is
// opaque to the hazard recognizer -> missing VALU-write->MFMA-read waits).
__device__ __forceinline__ unsigned cvtpk(float lo, float hi) {
    unsigned r;
    asm("v_cvt_pk_bf16_f32 %0, %1, %2" : "=v"(r) : "v"(lo), "v"(hi));
    return r;
}
__device__ __forceinline__ f32x4 mfma(bf16x8 a, bf16x8 b, f32x4 c) {
    return __builtin_amdgcn_mfma_f32_16x16x32_bf16(a, b, c, 0, 0, 0);
}
// ---- sigma-permuted A-fragment packs (NO cross-lane ops) ----
// Hardware k slot kq*8+e holds logical index sigma(kq,e)=(e>>2)*16+kq*4+(e&3).
// B-operands (adjacency, M) are stored with the same sigma on their k axis,
// so stage-1/stage-2 A-frags are pure per-lane cvtpk packs of D-tiles.
// HAZARD-HARDENED (r10/r12): one asm block per fragment, early-clobber
// outputs, trailing s_nop 3 = deterministic VALU->MFMA wait states.
__device__ __forceinline__ bf16x8 frag2(f32x4 A, f32x4 B) {
    union { bf16x8 v; unsigned u[4]; } r;
    asm("v_cvt_pk_bf16_f32 %0, %4, %5\n\t"
        "v_cvt_pk_bf16_f32 %1, %6, %7\n\t"
        "v_cvt_pk_bf16_f32 %2, %8, %9\n\t"
        "v_cvt_pk_bf16_f32 %3, %10, %11\n\t"
        "s_nop 3"
        : "=&v"(r.u[0]), "=&v"(r.u[1]), "=&v"(r.u[2]), "=&v"(r.u[3])
        : "v"(A[0]), "v"(A[1]), "v"(A[2]), "v"(A[3]),
          "v"(B[0]), "v"(B[1]), "v"(B[2]), "v"(B[3]));
    return r.v;
}
__device__ __forceinline__ bf16x8 frag1z(f32x4 A) {
    union { bf16x8 v; unsigned u[4]; } r;
    asm("v_cvt_pk_bf16_f32 %0, %2, %3\n\t"
        "v_cvt_pk_bf16_f32 %1, %4, %5\n\t"
        "s_nop 3"
        : "=&v"(r.u[0]), "=&v"(r.u[1])
        : "v"(A[0]), "v"(A[1]), "v"(A[2]), "v"(A[3]));
    r.u[2] = 0u; r.u[3] = 0u;
    return r.v;
}
// residual + relu, f32 register state
__device__ __forceinline__ void accRelu(f32x4 &S, f32x4 h) {
    S[0] += fmaxf(h[0], 0.f); S[1] += fmaxf(h[1], 0.f);
    S[2] += fmaxf(h[2], 0.f); S[3] += fmaxf(h[3], 0.f);
}

// ---------------------------------------------------------------------------
// Prep (tiny, one-shot): Tbf = bf16(emb@W_s2n * sT)  (100x32)
//   Mbf[lyr][row][64]: SIGMA-PERMUTED k axis — physical col c holds the
//   value for logical u = (c>>5)*32 + ((c&7)>>2)*16 + ((c>>3)&3)*4 + (c&3).
//   rows 0..31 = MsT[w][u], rows 32..47 = MvT[w][u]; logical u>=48 -> 0.
// ---------------------------------------------------------------------------
__global__ void prep_kernel(const float* __restrict__ emb,
                            const float* __restrict__ W_s2n,
                            const float* __restrict__ W1, const float* __restrict__ W2,
                            const float* __restrict__ W3, const float* __restrict__ W4,
                            const float* __restrict__ Ws, const float* __restrict__ Wv,
                            ushort* __restrict__ Tbf, ushort* __restrict__ Mbf)
{
    int idx = blockIdx.x * blockDim.x + threadIdx.x;
    if (idx < 3200) {
        int r = idx >> 5, c = idx & 31;
        float acc = 0.f;
        for (int k = 0; k < 32; ++k) acc += emb[r*32 + k] * W_s2n[k*32 + c];
        Tbf[idx] = f2bf(acc * SCALE_T);
        return;
    }
    idx -= 3200;
    if (idx < 3*48*64) {
        int lyr = idx / 3072, rem = idx % 3072;
        int row = rem >> 6, c = rem & 63;
        // physical col c -> logical u via sigma
        int kc = c >> 5, c5 = c & 31, kq2 = c5 >> 3, e = c5 & 7;
        int u = kc*32 + (e >> 2)*16 + kq2*4 + (e & 3);
        float val = 0.f;
        if (row < 32) {
            int w = row;
            if (u < 32) {
                float a = 0.f;
                for (int k = 0; k < 32; ++k)
                    a += W1[lyr*1024 + u*32 + k] * Ws[lyr*1024 + k*32 + w];
                val = a * SCALE_M1;
            } else if (u < 48) {
                int uu = u - 32; float a = 0.f;
                for (int k = 0; k < 32; ++k)
                    a += W4[lyr*512 + uu*32 + k] * Ws[lyr*1024 + k*32 + w];
                val = a * SCALE_M2;
            }
        } else {
            int w = row - 32;
            if (u < 32) {
                float a = 0.f;
                for (int k = 0; k < 16; ++k)
                    a += W2[lyr*512 + u*16 + k] * Wv[lyr*256 + k*16 + w];
                val = a * SCALE_M34;
            } else if (u < 48) {
                int uu = u - 32; float a = 0.f;
                for (int k = 0; k < 16; ++k)
                    a += W3[lyr*256 + uu*16 + k] * Wv[lyr*256 + k*16 + w];
                val = a * SCALE_M34;
            }
        }
        Mbf[lyr*3072 + row*64 + c] = f2bf(val);
    }
}

// ---------------------------------------------------------------------------
// Fused GNN + MLP: one wave = one graph; 4 graphs/block; 512 blocks.
// Feature state in f32 registers (Ss[2][2], Sv[2][3], D-layout). The
// sigma-permuted k axis makes every A-fragment a pure per-lane cvtpk pack
// of D-tiles — ZERO permlane/LDS in the layer loop. (r13 ablation: 2
// graphs/wave at 1 wave/SIMD regressed 8.5us — asm pack units are atomic
// to the scheduler, so in-wave ILP cannot replace co-resident-wave TLP.)
// ---------------------------------------------------------------------------
__global__ __launch_bounds__(256)
void gnn_kernel(const float* __restrict__ pos, const int* __restrict__ z,
                const ushort* __restrict__ Tbf, const ushort* __restrict__ Mbf,
                const float* __restrict__ Wr1, const float* __restrict__ br1,
                const float* __restrict__ Wr2, const float* __restrict__ br2,
                float* __restrict__ out, int B)
{
    __shared__ __align__(16) char smem[26880];
    ushort* featA = (ushort*)smem;                    // 4*80*40*2 = 25600 B
    float*  hgl   = (float*)(smem + 25600);           // 4*80*4    = 1280 B
    float*  h1    = (float*)smem;                     // alias featA (post-layers)
    float*  red   = (float*)(smem + 4096);            // alias featA, after h1

    const int tid = threadIdx.x;
    const int wv = tid >> 6, l = tid & 63;
    const int g  = blockIdx.x*4 + wv;
    ushort* F  = featA + wv*80*FSTR;
    const int ln = l & 15, kq = l >> 4;

    // s init: F[c][n] = Tbf[z[n]][c]  (transposed scatter, wave-private)
    {
        int n = l & 31, h = l >> 5;
        int zg = z[g*32 + n];
        uint4 t0 = *(const uint4*)(Tbf + zg*32 + h*16);
        uint4 t1 = *(const uint4*)(Tbf + zg*32 + h*16 + 8);
        unsigned ua[8] = {t0.x, t0.y, t0.z, t0.w, t1.x, t1.y, t1.z, t1.w};
        #pragma unroll
        for (int q = 0; q < 8; ++q) {
            F[(h*16 + 2*q    )*FSTR + n] = (ushort)ua[q];
            F[(h*16 + 2*q + 1)*FSTR + n] = (ushort)(ua[q] >> 16);
        }
    }

    // register feature state, D-layout: lane=channel, regs=node (mt*16+kq*4+q)
    f32x4 Ss[2][2];            // [node-tile][s-ch-tile]
    f32x4 Sv[2][3];            // [node-tile][spatial i], v-ch = lane
    #pragma unroll
    for (int mt = 0; mt < 2; ++mt) {
        #pragma unroll
        for (int wt = 0; wt < 2; ++wt) {
            uint2 d = *(const uint2*)&F[(wt*16 + ln)*FSTR + mt*16 + kq*4];
            Ss[mt][wt][0] = bf2f((ushort)(d.x      ));
            Ss[mt][wt][1] = bf2f((ushort)(d.x >> 16));
            Ss[mt][wt][2] = bf2f((ushort)(d.y      ));
            Ss[mt][wt][3] = bf2f((ushort)(d.y >> 16));
        }
        #pragma unroll
        for (int i = 0; i < 3; ++i)
            Sv[mt][i] = (f32x4){0.f, 0.f, 0.f, 0.f};
    }

    // adjacency fragments, sigma-permuted k (src = (jj>>2)*16 + kq*4 + (jj&3))
    bf16x8 adjf[4][2];
    {
        #pragma unroll
        for (int nt = 0; nt < 2; ++nt) {
            int ng = g*32 + nt*16 + ln;
            float px = pos[3*ng], py = pos[3*ng+1], pz = pos[3*ng+2];
            union { bf16x8 v; ushort s[8]; } o[4];
            #pragma unroll
            for (int jj = 0; jj < 8; ++jj) {
                int j = g*32 + ((jj >> 2) << 4) + kq*4 + (jj & 3);
                float dx = __fsub_rn(px, pos[3*j]);
                float dy = __fsub_rn(py, pos[3*j+1]);
                float dz = __fsub_rn(pz, pos[3*j+2]);
                float d2 = __fadd_rn(__fadd_rn(__fmul_rn(dx,dx), __fmul_rn(dy,dy)),
                                     __fmul_rn(dz,dz));
                bool on = (d2 <= 25.0f) && (d2 > 0.0f);
                float rinv = on ? rsqrtf(d2) * SQRT3F : 0.f;
                o[0].s[jj] = on ? (ushort)0x3F80 : (ushort)0;   // bf16(1.0)
                o[1].s[jj] = f2bf(dx * rinv);
                o[2].s[jj] = f2bf(dy * rinv);
                o[3].s[jj] = f2bf(dz * rinv);
            }
            #pragma unroll
            for (int w = 0; w < 4; ++w) adjf[w][nt] = o[w].v;
        }
    }

    const f32x4 z4 = {0.f, 0.f, 0.f, 0.f};

    for (int lay = 0; lay < 3; ++lay) {
        const ushort* Mg = Mbf + lay*3072;
        // A-frags from register state: pure cvtpk packs (sigma layout)
        bf16x8 fs0 = frag2(Ss[0][0], Ss[1][0]);
        bf16x8 fs1 = frag2(Ss[0][1], Ss[1][1]);
        bf16x8 fv0 = frag2(Sv[0][0], Sv[1][0]);
        bf16x8 fv1 = frag2(Sv[0][1], Sv[1][1]);
        bf16x8 fv2 = frag2(Sv[0][2], Sv[1][2]);
        // M fragments for this layer (global, L1-hot; sigma baked in by prep)
        bf16x8 bmS0[2], bmS1[2], bmV[2];
        #pragma unroll
        for (int kc = 0; kc < 2; ++kc) {
            bmS0[kc] = *(const bf16x8*)&Mg[(     ln)*64 + kc*32 + kq*8];
            bmS1[kc] = *(const bf16x8*)&Mg[(16 + ln)*64 + kc*32 + kq*8];
            bmV [kc] = *(const bf16x8*)&Mg[(32 + ln)*64 + kc*32 + kq*8];
        }

        bf16x8 agf[2][2];   // [node-tile][k-block] stage-2 A fragments

        // ---- scalar path: agg rows = [A0*s (u<32) | sum_i Ai*v_i (u32..47)]
        #pragma unroll
        for (int nt = 0; nt < 2; ++nt) {
            f32x4 T0 = mfma(fs0, adjf[0][nt], z4);
            f32x4 T1 = mfma(fs1, adjf[0][nt], z4);
            f32x4 T2 = mfma(fv2, adjf[3][nt], z4);
            T2 = mfma(fv1, adjf[2][nt], T2);
            T2 = mfma(fv0, adjf[1][nt], T2);
            agf[nt][0] = frag2(T0, T1);
            agf[nt][1] = frag1z(T2);
        }
        f32x4 hs[2][2] = {{z4, z4}, {z4, z4}};   // [node-tile][w-tile]
        #pragma unroll
        for (int kc = 0; kc < 2; ++kc)
            #pragma unroll
            for (int mt = 0; mt < 2; ++mt) {
                hs[mt][0] = mfma(agf[mt][kc], bmS0[kc], hs[mt][0]);
                hs[mt][1] = mfma(agf[mt][kc], bmS1[kc], hs[mt][1]);
            }
        #pragma unroll
        for (int mt = 0; mt < 2; ++mt)
            #pragma unroll
            for (int wt = 0; wt < 2; ++wt)
                accRelu(Ss[mt][wt], hs[mt][wt]);

        // ---- vector path, one spatial component i at a time
        #pragma unroll
        for (int i = 0; i < 3; ++i) {
            bf16x8 fvi = (i == 0) ? fv0 : (i == 1) ? fv1 : fv2;
            #pragma unroll
            for (int nt = 0; nt < 2; ++nt) {
                f32x4 T0 = mfma(fs0, adjf[1+i][nt], z4);
                f32x4 T1 = mfma(fs1, adjf[1+i][nt], z4);
                f32x4 T2 = mfma(fvi, adjf[0][nt], z4);
                agf[nt][0] = frag2(T0, T1);
                agf[nt][1] = frag1z(T2);
            }
            f32x4 hv[2] = {z4, z4};
            #pragma unroll
            for (int kc = 0; kc < 2; ++kc)
                #pragma unroll
                for (int mt = 0; mt < 2; ++mt)
                    hv[mt] = mfma(agf[mt][kc], bmV[kc], hv[mt]);
            #pragma unroll
            for (int mt = 0; mt < 2; ++mt)
                accRelu(Sv[mt][i], hv[mt]);
        }
    }

    // write state back to F (bf16) for the pooling pass
    #pragma unroll
    for (int mt = 0; mt < 2; ++mt) {
        #pragma unroll
        for (int wt = 0; wt < 2; ++wt) {
            uint2 w;
            w.x = cvtpk(Ss[mt][wt][0], Ss[mt][wt][1]);
            w.y = cvtpk(Ss[mt][wt][2], Ss[mt][wt][3]);
            *(uint2*)&F[(wt*16 + ln)*FSTR + mt*16 + kq*4] = w;
        }
        #pragma unroll
        for (int i = 0; i < 3; ++i) {
            uint2 w;
            w.x = cvtpk(Sv[mt][i][0], Sv[mt][i][1]);
            w.y = cvtpk(Sv[mt][i][2], Sv[mt][i][3]);
            *(uint2*)&F[(32 + i*16 + ln)*FSTR + mt*16 + kq*4] = w;
        }
    }

    // wave-local sum-pool -> hgl[wv][80]
    for (int f = l; f < 80; f += 64) {
        const ushort* row;
        if (f < 32) row = &F[f*FSTR];
        else { int c = f - 32, w = c/3, i = c - 3*w; row = &F[(32 + i*16 + w)*FSTR]; }
        const uint* r32 = (const uint*)row;
        float acc = 0.f;
        #pragma unroll
        for (int q = 0; q < 16; ++q) {
            uint u = r32[q];
            acc += bf2f((ushort)u) + bf2f((ushort)(u >> 16));
        }
        hgl[wv*80 + f] = acc;
    }
    __syncthreads();   // hgl complete; featA (F) dead -> h1/red alias safe

    // --- fused MLP head (block = its 4 graphs) ---
    {
        const int w = tid;
        float acc0 = br1[w];
        float acc1 = acc0, acc2 = acc0, acc3 = acc0;
        #pragma unroll 4
        for (int f = 0; f < 80; ++f) {
            float wvv = Wr1[f*256 + w];
            acc0 = fmaf(hgl[0*80 + f], wvv, acc0);
            acc1 = fmaf(hgl[1*80 + f], wvv, acc1);
            acc2 = fmaf(hgl[2*80 + f], wvv, acc2);
            acc3 = fmaf(hgl[3*80 + f], wvv, acc3);
        }
        h1[0*256 + w] = fmaxf(acc0, 0.f);
        h1[1*256 + w] = fmaxf(acc1, 0.f);
        h1[2*256 + w] = fmaxf(acc2, 0.f);
        h1[3*256 + w] = fmaxf(acc3, 0.f);
    }
    __syncthreads();
    {
        const int g0 = blockIdx.x * 4;
        const int w2 = tid & 127, kh = tid >> 7;
        const float4* h1v = (const float4*)h1;   // [4][64] float4 view
        float s0 = 0.f, s1 = 0.f, s2 = 0.f, s3 = 0.f;
        #pragma unroll 2
        for (int k4 = kh*32; k4 < kh*32 + 32; ++k4) {
            float4 hA = h1v[0*64 + k4];
            float4 hB = h1v[1*64 + k4];
            float4 hC = h1v[2*64 + k4];
            float4 hD = h1v[3*64 + k4];
            int k = k4 * 4;
            float m0 = Wr2[(size_t)(k+0)*128 + w2];
            float m1 = Wr2[(size_t)(k+1)*128 + w2];
            float m2 = Wr2[(size_t)(k+2)*128 + w2];
            float m3 = Wr2[(size_t)(k+3)*128 + w2];
            s0 = fmaf(hA.x,m0, fmaf(hA.y,m1, fmaf(hA.z,m2, fmaf(hA.w,m3, s0))));
            s1 = fmaf(hB.x,m0, fmaf(hB.y,m1, fmaf(hB.z,m2, fmaf(hB.w,m3, s1))));
            s2 = fmaf(hC.x,m0, fmaf(hC.y,m1, fmaf(hC.z,m2, fmaf(hC.w,m3, s2))));
            s3 = fmaf(hD.x,m0, fmaf(hD.y,m1, fmaf(hD.z,m2, fmaf(hD.w,m3, s3))));
        }
        if (kh) {
            red[0*128 + w2] = s0; red[1*128 + w2] = s1;
            red[2*128 + w2] = s2; red[3*128 + w2] = s3;
        }
        __syncthreads();
        if (!kh) {
            float b = br2[w2];
            out[(size_t)(g0+0)*128 + w2] = s0 + red[0*128 + w2] + b;
            out[(size_t)(g0+1)*128 + w2] = s1 + red[1*128 + w2] + b;
            out[(size_t)(g0+2)*128 + w2] = s2 + red[2*128 + w2] + b;
            out[(size_t)(g0+3)*128 + w2] = s3 + red[3*128 + w2] + b;
        }
    }
}

// ---------------------------------------------------------------------------
extern "C" void kernel_launch(void* const* d_in, const int* in_sizes, int n_in,
                              void* d_out, int out_size, void* d_ws, size_t ws_size,
                              hipStream_t stream)
{
    const float* pos   = (const float*)d_in[0];
    const int*   z     = (const int*)d_in[1];
    const float* emb   = (const float*)d_in[5];
    const float* W_s2n = (const float*)d_in[6];
    const float* W1    = (const float*)d_in[7];
    const float* W2    = (const float*)d_in[8];
    const float* W3    = (const float*)d_in[9];
    const float* W4    = (const float*)d_in[10];
    const float* Ws    = (const float*)d_in[11];
    const float* Wv    = (const float*)d_in[12];
    const float* Wr1   = (const float*)d_in[13];
    const float* br1   = (const float*)d_in[14];
    const float* Wr2   = (const float*)d_in[15];
    const float* br2   = (const float*)d_in[16];
    float* out = (float*)d_out;

    const int B = out_size / 128;      // graphs (2048)

    // workspace: Tbf (3200 shorts) | Mbf (9216 shorts)
    char* p = (char*)d_ws;
    ushort* Tbf = (ushort*)p;  p += 6400;
    ushort* Mbf = (ushort*)p;  p += 18432;

    const int prep_total = 3200 + 3*48*64;
    prep_kernel<<<(prep_total + 255) / 256, 256, 0, stream>>>(
        emb, W_s2n, W1, W2, W3, W4, Ws, Wv, Tbf, Mbf);

    gnn_kernel<<<B / 4, 256, 0, stream>>>(pos, z, Tbf, Mbf,
                                          Wr1, br1, Wr2, br2, out, B);
}